// Round 1
// baseline (748.723 us; speedup 1.0000x reference)
//
#include <hip/hip_runtime.h>
#include <hip/hip_bf16.h>

#define N_NODES  20000
#define N_EDGES  320000
#define E_TOT    (N_EDGES + N_NODES)   /* 340000 incl. self loops */
#define N_GRAPHS 512
#define H1 10
#define C1 78
#define F1 780                          /* H1*C1 */
#define C2 100
#define NEG_SLOPE 0.2f

/* ---------------- CSR build (by destination) ---------------- */

__global__ void k_count(const int* __restrict__ ei, int* __restrict__ cnt) {
  int e = blockIdx.x * blockDim.x + threadIdx.x;
  if (e >= E_TOT) return;
  int dst = (e < N_EDGES) ? ei[N_EDGES + e] : (e - N_EDGES);
  atomicAdd(&cnt[dst], 1);
}

__global__ void k_scan(const int* __restrict__ cnt, int* __restrict__ offs, int n) {
  __shared__ int sh[256];
  __shared__ int carrySh;
  if (threadIdx.x == 0) carrySh = 0;
  __syncthreads();
  for (int base = 0; base < n; base += 256) {
    int i = base + (int)threadIdx.x;
    int v = (i < n) ? cnt[i] : 0;
    sh[threadIdx.x] = v;
    __syncthreads();
    for (int o = 1; o < 256; o <<= 1) {
      int t = (threadIdx.x >= (unsigned)o) ? sh[threadIdx.x - o] : 0;
      __syncthreads();
      sh[threadIdx.x] += t;
      __syncthreads();
    }
    int carry = carrySh;
    if (i < n) offs[i + 1] = carry + sh[threadIdx.x];
    if (base == 0 && threadIdx.x == 0) offs[0] = 0;
    __syncthreads();
    if (threadIdx.x == 255) carrySh = carry + sh[255];
    __syncthreads();
  }
}

__global__ void k_scatter(const int* __restrict__ ei, const int* __restrict__ offs,
                          int* __restrict__ cursor, int* __restrict__ srcs) {
  int e = blockIdx.x * blockDim.x + threadIdx.x;
  if (e >= E_TOT) return;
  int src, dst;
  if (e < N_EDGES) { src = ei[e]; dst = ei[N_EDGES + e]; }
  else             { src = dst = e - N_EDGES; }
  int pos = offs[dst] + atomicAdd(&cursor[dst], 1);
  srcs[pos] = src;
}

/* ---------------- generic fp32 GEMM: C[M,N] = A[M,K] @ B[K,N] ---------------- */

__global__ __launch_bounds__(256) void k_gemm(const float* __restrict__ A,
                                              const float* __restrict__ B,
                                              float* __restrict__ C,
                                              int M, int N, int K) {
  __shared__ float As[16][64];
  __shared__ float Bs[16][64];
  int tid = threadIdx.x;
  int tx = tid & 15, ty = tid >> 4;
  int m0 = blockIdx.y * 64, n0 = blockIdx.x * 64;
  float acc[4][4] = {};
  for (int k0 = 0; k0 < K; k0 += 16) {
#pragma unroll
    for (int i = 0; i < 4; i++) {
      int li = tid * 4 + i;
      int r = li >> 4, c = li & 15;
      float v = 0.f;
      if (m0 + r < M && k0 + c < K) v = A[(size_t)(m0 + r) * K + k0 + c];
      As[c][r] = v;
    }
#pragma unroll
    for (int i = 0; i < 4; i++) {
      int li = tid * 4 + i;
      int kk = li >> 6, j = li & 63;
      float v = 0.f;
      if (k0 + kk < K && n0 + j < N) v = B[(size_t)(k0 + kk) * N + n0 + j];
      Bs[kk][j] = v;
    }
    __syncthreads();
#pragma unroll
    for (int kk = 0; kk < 16; kk++) {
      float a[4], b[4];
#pragma unroll
      for (int i = 0; i < 4; i++) a[i] = As[kk][ty * 4 + i];
#pragma unroll
      for (int i = 0; i < 4; i++) b[i] = Bs[kk][tx * 4 + i];
#pragma unroll
      for (int i = 0; i < 4; i++)
#pragma unroll
        for (int j = 0; j < 4; j++) acc[i][j] += a[i] * b[j];
    }
    __syncthreads();
  }
  for (int i = 0; i < 4; i++) {
    int m = m0 + ty * 4 + i;
    if (m >= M) continue;
    for (int j = 0; j < 4; j++) {
      int n = n0 + tx * 4 + j;
      if (n < N) C[(size_t)m * N + n] = acc[i][j];
    }
  }
}

/* ---------------- attention logits: per (node,head) dot ---------------- */

__global__ void k_alpha1(const float* __restrict__ h1, const float* __restrict__ a_src,
                         const float* __restrict__ a_dst, float* __restrict__ as,
                         float* __restrict__ ad) {
  int t = blockIdx.x * blockDim.x + threadIdx.x;
  if (t >= N_NODES * H1) return;
  int n = t / H1, h = t % H1;
  const float* row = h1 + (size_t)n * F1 + h * C1;
  const float* ws = a_src + h * C1;
  const float* wd = a_dst + h * C1;
  float s0 = 0.f, s1 = 0.f;
  for (int c = 0; c < C1; c++) { float v = row[c]; s0 += v * ws[c]; s1 += v * wd[c]; }
  as[t] = s0; ad[t] = s1;
}

__global__ void k_alpha2(const float* __restrict__ z2, const float* __restrict__ a_src,
                         const float* __restrict__ a_dst, float* __restrict__ as,
                         float* __restrict__ ad) {
  int n = blockIdx.x * blockDim.x + threadIdx.x;
  if (n >= N_NODES) return;
  const float* row = z2 + (size_t)n * C2;
  float s0 = 0.f, s1 = 0.f;
  for (int c = 0; c < C2; c++) { float v = row[c]; s0 += v * a_src[c]; s1 += v * a_dst[c]; }
  as[n] = s0; ad[n] = s1;
}

/* ---------------- layer-1 GAT: wave per (dst,head), softmax + aggregate + bias + ELU -------- */

__global__ __launch_bounds__(256) void k_gat1(const float* __restrict__ h1,
                                              const float* __restrict__ as,
                                              const float* __restrict__ ad,
                                              const int* __restrict__ offs,
                                              const int* __restrict__ srcs,
                                              const float* __restrict__ b1,
                                              float* __restrict__ out) {
  int wid = (blockIdx.x * 256 + threadIdx.x) >> 6;
  int lane = threadIdx.x & 63;
  if (wid >= N_NODES * H1) return;
  int n = wid / H1, h = wid % H1;
  int beg = offs[n], deg = offs[n + 1] - beg;
  float adv = ad[n * H1 + h];

  float m = -INFINITY;
  for (int i = lane; i < deg; i += 64) {
    float e = as[srcs[beg + i] * H1 + h] + adv;
    e = (e > 0.f) ? e : NEG_SLOPE * e;
    m = fmaxf(m, e);
  }
#pragma unroll
  for (int o = 32; o; o >>= 1) m = fmaxf(m, __shfl_xor(m, o));

  float ssum = 0.f;
  for (int i = lane; i < deg; i += 64) {
    float e = as[srcs[beg + i] * H1 + h] + adv;
    e = (e > 0.f) ? e : NEG_SLOPE * e;
    ssum += __expf(e - m);
  }
#pragma unroll
  for (int o = 32; o; o >>= 1) ssum += __shfl_xor(ssum, o);
  float inv = 1.f / (ssum + 1e-16f);

  float acc0 = 0.f, acc1 = 0.f;
  for (int chunk = 0; chunk < deg; chunk += 64) {
    int i = chunk + lane;
    float w = 0.f; int s = 0;
    if (i < deg) {
      s = srcs[beg + i];
      float e = as[s * H1 + h] + adv;
      e = (e > 0.f) ? e : NEG_SLOPE * e;
      w = __expf(e - m) * inv;
    }
    int cl = min(64, deg - chunk);
    for (int j = 0; j < cl; j++) {
      float wj = __shfl(w, j);
      int sj = __shfl(s, j);
      const float* row = h1 + (size_t)sj * F1 + h * C1;
      acc0 += wj * row[lane];
      if (lane < C1 - 64) acc1 += wj * row[64 + lane];
    }
  }
  int ob = n * F1 + h * C1;
  float v0 = acc0 + b1[h * C1 + lane];
  out[ob + lane] = (v0 > 0.f) ? v0 : (__expf(v0) - 1.f);
  if (lane < C1 - 64) {
    float v1 = acc1 + b1[h * C1 + 64 + lane];
    out[ob + 64 + lane] = (v1 > 0.f) ? v1 : (__expf(v1) - 1.f);
  }
}

/* ---------------- layer-2 GAT: wave per dst, 1 head, 100 ch, + bias + ReLU ---------------- */

__global__ __launch_bounds__(256) void k_gat2(const float* __restrict__ z2,
                                              const float* __restrict__ as,
                                              const float* __restrict__ ad,
                                              const int* __restrict__ offs,
                                              const int* __restrict__ srcs,
                                              const float* __restrict__ b2,
                                              float* __restrict__ h2) {
  int wid = (blockIdx.x * 256 + threadIdx.x) >> 6;
  int lane = threadIdx.x & 63;
  if (wid >= N_NODES) return;
  int n = wid;
  int beg = offs[n], deg = offs[n + 1] - beg;
  float adv = ad[n];

  float m = -INFINITY;
  for (int i = lane; i < deg; i += 64) {
    float e = as[srcs[beg + i]] + adv;
    e = (e > 0.f) ? e : NEG_SLOPE * e;
    m = fmaxf(m, e);
  }
#pragma unroll
  for (int o = 32; o; o >>= 1) m = fmaxf(m, __shfl_xor(m, o));

  float ssum = 0.f;
  for (int i = lane; i < deg; i += 64) {
    float e = as[srcs[beg + i]] + adv;
    e = (e > 0.f) ? e : NEG_SLOPE * e;
    ssum += __expf(e - m);
  }
#pragma unroll
  for (int o = 32; o; o >>= 1) ssum += __shfl_xor(ssum, o);
  float inv = 1.f / (ssum + 1e-16f);

  float acc0 = 0.f, acc1 = 0.f;
  for (int chunk = 0; chunk < deg; chunk += 64) {
    int i = chunk + lane;
    float w = 0.f; int s = 0;
    if (i < deg) {
      s = srcs[beg + i];
      float e = as[s] + adv;
      e = (e > 0.f) ? e : NEG_SLOPE * e;
      w = __expf(e - m) * inv;
    }
    int cl = min(64, deg - chunk);
    for (int j = 0; j < cl; j++) {
      float wj = __shfl(w, j);
      int sj = __shfl(s, j);
      const float* row = z2 + (size_t)sj * C2;
      acc0 += wj * row[lane];
      if (lane < C2 - 64) acc1 += wj * row[64 + lane];
    }
  }
  float v0 = acc0 + b2[lane];
  h2[(size_t)n * C2 + lane] = fmaxf(v0, 0.f);
  if (lane < C2 - 64) {
    float v1 = acc1 + b2[64 + lane];
    h2[(size_t)n * C2 + 64 + lane] = fmaxf(v1, 0.f);
  }
}

/* ---------------- global max pool (h2 >= 0, so uint atomicMax with 0-init is exact) -------- */

__global__ void k_pool(const float* __restrict__ h2, const int* __restrict__ batch,
                       unsigned int* __restrict__ pool) {
  int t = blockIdx.x * blockDim.x + threadIdx.x;
  if (t >= N_NODES * C2) return;
  int n = t / C2, c = t % C2;
  int g = batch[n];
  atomicMax(&pool[g * C2 + c], __float_as_uint(h2[t]));
}

/* ---------------- head: out = relu(pool @ Wg + bg) ---------------- */

__global__ __launch_bounds__(128) void k_head(const float* __restrict__ pool,
                                              const float* __restrict__ Wg,
                                              const float* __restrict__ bg,
                                              float* __restrict__ out) {
  __shared__ float row[C2];
  int g = blockIdx.x;
  if (threadIdx.x < C2) row[threadIdx.x] = pool[g * C2 + threadIdx.x];
  __syncthreads();
  int c = threadIdx.x;
  if (c < C2) {
    float acc = bg[c];
    for (int k = 0; k < C2; k++) acc += row[k] * Wg[k * C2 + c];
    out[g * C2 + c] = fmaxf(acc, 0.f);
  }
}

/* ---------------- launch ---------------- */

extern "C" void kernel_launch(void* const* d_in, const int* in_sizes, int n_in,
                              void* d_out, int out_size, void* d_ws, size_t ws_size,
                              hipStream_t stream) {
  const float* x      = (const float*)d_in[0];
  const int*   ei     = (const int*)d_in[1];
  const int*   batch  = (const int*)d_in[2];
  const float* W1     = (const float*)d_in[4];
  const float* a_src1 = (const float*)d_in[5];
  const float* a_dst1 = (const float*)d_in[6];
  const float* b1     = (const float*)d_in[7];
  const float* W2     = (const float*)d_in[8];
  const float* a_src2 = (const float*)d_in[9];
  const float* a_dst2 = (const float*)d_in[10];
  const float* b2     = (const float*)d_in[11];
  const float* Wg     = (const float*)d_in[12];
  const float* bg     = (const float*)d_in[13];
  float* out = (float*)d_out;

  char* w = (char*)d_ws;
  size_t off = 0;
  auto alloc = [&](size_t bytes) -> void* {
    void* p = w + off;
    off += (bytes + 255) & ~(size_t)255;
    return p;
  };

  float* h1  = (float*)alloc((size_t)N_NODES * F1 * 4);   /* 62.4 MB */
  float* ha  = (float*)alloc((size_t)N_NODES * F1 * 4);   /* 62.4 MB */
  float* as1 = (float*)alloc((size_t)N_NODES * H1 * 4);
  float* ad1 = (float*)alloc((size_t)N_NODES * H1 * 4);
  int* cnt    = (int*)alloc((size_t)N_NODES * 4);
  int* cursor = (int*)alloc((size_t)N_NODES * 4);
  int* offs   = (int*)alloc((size_t)(N_NODES + 1) * 4);
  int* srcs   = (int*)alloc((size_t)E_TOT * 4);

  /* layer-2 buffers alias dead h1 region (h1 unused after k_gat1) */
  float* z2  = h1;                       /* 20000*100 */
  float* h2  = z2 + (size_t)N_NODES * C2;
  float* as2 = h2 + (size_t)N_NODES * C2;
  float* ad2 = as2 + N_NODES;
  unsigned int* pool = (unsigned int*)(ad2 + N_NODES);

  hipMemsetAsync(cnt, 0, (size_t)N_NODES * 4, stream);
  hipMemsetAsync(cursor, 0, (size_t)N_NODES * 4, stream);

  k_count<<<(E_TOT + 255) / 256, 256, 0, stream>>>(ei, cnt);
  k_scan<<<1, 256, 0, stream>>>(cnt, offs, N_NODES);
  k_scatter<<<(E_TOT + 255) / 256, 256, 0, stream>>>(ei, offs, cursor, srcs);

  /* GEMM1: h1 = x @ W1   (20000x780x78) */
  k_gemm<<<dim3((F1 + 63) / 64, (N_NODES + 63) / 64), 256, 0, stream>>>(x, W1, h1,
                                                                        N_NODES, F1, C1);
  k_alpha1<<<(N_NODES * H1 + 255) / 256, 256, 0, stream>>>(h1, a_src1, a_dst1, as1, ad1);
  k_gat1<<<(N_NODES * H1) / 4, 256, 0, stream>>>(h1, as1, ad1, offs, srcs, b1, ha);

  /* GEMM2: z2 = ha @ W2   (20000x100x780) -- z2 aliases h1 (dead) */
  k_gemm<<<dim3((C2 + 63) / 64, (N_NODES + 63) / 64), 256, 0, stream>>>(ha, W2, z2,
                                                                        N_NODES, C2, F1);
  k_alpha2<<<(N_NODES + 255) / 256, 256, 0, stream>>>(z2, a_src2, a_dst2, as2, ad2);
  k_gat2<<<N_NODES / 4, 256, 0, stream>>>(z2, as2, ad2, offs, srcs, b2, h2);

  hipMemsetAsync(pool, 0, (size_t)N_GRAPHS * C2 * 4, stream);
  k_pool<<<(N_NODES * C2 + 255) / 256, 256, 0, stream>>>(h2, batch, pool);
  k_head<<<N_GRAPHS, 128, 0, stream>>>((const float*)pool, Wg, bg, out);
}

// Round 2
// 543.898 us; speedup vs baseline: 1.3766x; 1.3766x over previous
//
#include <hip/hip_runtime.h>
#include <hip/hip_bf16.h>

#define N_NODES  20000
#define N_EDGES  320000
#define E_TOT    (N_EDGES + N_NODES)   /* 340000 incl. self loops */
#define N_GRAPHS 512
#define H1 10
#define C1 78
#define F1 780                          /* H1*C1 */
#define C2 100
#define NEG_SLOPE 0.2f

__device__ __forceinline__ float bf_lo(unsigned int u) { return __uint_as_float(u << 16); }
__device__ __forceinline__ float bf_hi(unsigned int u) { return __uint_as_float(u & 0xFFFF0000u); }

/* ---------------- CSR build (by destination) ---------------- */

__global__ void k_count(const int* __restrict__ ei, int* __restrict__ cnt) {
  int e = blockIdx.x * blockDim.x + threadIdx.x;
  if (e >= E_TOT) return;
  int dst = (e < N_EDGES) ? ei[N_EDGES + e] : (e - N_EDGES);
  atomicAdd(&cnt[dst], 1);
}

/* single-block scan: 1024 threads x 20 elems, shfl wave scans */
__global__ __launch_bounds__(1024) void k_scan(const int* __restrict__ cnt,
                                               int* __restrict__ offs, int n) {
  const int PER = 20;
  int t = threadIdx.x;
  int lane = t & 63, wv = t >> 6;
  int base = t * PER;
  int loc[PER];
  int run = 0;
#pragma unroll
  for (int k = 0; k < PER; k++) {
    int idx = base + k;
    int v = (idx < n) ? cnt[idx] : 0;
    run += v;
    loc[k] = run;
  }
  int total = run;
  /* wave inclusive scan of totals */
  int sc = total;
#pragma unroll
  for (int o = 1; o < 64; o <<= 1) {
    int u = __shfl_up(sc, o);
    if (lane >= o) sc += u;
  }
  __shared__ int ws[16];
  if (lane == 63) ws[wv] = sc;
  __syncthreads();
  if (t == 0) {
    int r = 0;
#pragma unroll
    for (int i = 0; i < 16; i++) { int v = ws[i]; ws[i] = r; r += v; }
  }
  __syncthreads();
  int excl = ws[wv] + sc - total;   /* exclusive prefix for this thread's chunk */
#pragma unroll
  for (int k = 0; k < PER; k++) {
    int idx = base + k;
    if (idx < n) offs[idx + 1] = excl + loc[k];
  }
  if (t == 0) offs[0] = 0;
}

__global__ void k_scatter(const int* __restrict__ ei, const int* __restrict__ offs,
                          int* __restrict__ cursor, int* __restrict__ srcs) {
  int e = blockIdx.x * blockDim.x + threadIdx.x;
  if (e >= E_TOT) return;
  int src, dst;
  if (e < N_EDGES) { src = ei[e]; dst = ei[N_EDGES + e]; }
  else             { src = dst = e - N_EDGES; }
  int pos = offs[dst] + atomicAdd(&cursor[dst], 1);
  srcs[pos] = src;
}

/* ---------------- generic fp32 GEMM: C[M,N] = A[M,K] @ B[K,N] ---------------- */

__global__ __launch_bounds__(256) void k_gemm(const float* __restrict__ A,
                                              const float* __restrict__ B,
                                              float* __restrict__ C,
                                              int M, int N, int K) {
  __shared__ float As[16][64];
  __shared__ float Bs[16][64];
  int tid = threadIdx.x;
  int tx = tid & 15, ty = tid >> 4;
  int m0 = blockIdx.y * 64, n0 = blockIdx.x * 64;
  float acc[4][4] = {};
  for (int k0 = 0; k0 < K; k0 += 16) {
#pragma unroll
    for (int i = 0; i < 4; i++) {
      int li = tid * 4 + i;
      int r = li >> 4, c = li & 15;
      float v = 0.f;
      if (m0 + r < M && k0 + c < K) v = A[(size_t)(m0 + r) * K + k0 + c];
      As[c][r] = v;
    }
#pragma unroll
    for (int i = 0; i < 4; i++) {
      int li = tid * 4 + i;
      int kk = li >> 6, j = li & 63;
      float v = 0.f;
      if (k0 + kk < K && n0 + j < N) v = B[(size_t)(k0 + kk) * N + n0 + j];
      Bs[kk][j] = v;
    }
    __syncthreads();
#pragma unroll
    for (int kk = 0; kk < 16; kk++) {
      float a[4], b[4];
#pragma unroll
      for (int i = 0; i < 4; i++) a[i] = As[kk][ty * 4 + i];
#pragma unroll
      for (int i = 0; i < 4; i++) b[i] = Bs[kk][tx * 4 + i];
#pragma unroll
      for (int i = 0; i < 4; i++)
#pragma unroll
        for (int j = 0; j < 4; j++) acc[i][j] += a[i] * b[j];
    }
    __syncthreads();
  }
  for (int i = 0; i < 4; i++) {
    int m = m0 + ty * 4 + i;
    if (m >= M) continue;
    for (int j = 0; j < 4; j++) {
      int n = n0 + tx * 4 + j;
      if (n < N) C[(size_t)m * N + n] = acc[i][j];
    }
  }
}

/* GEMM1 variant: x@W1 with bf16 head-major output h1b[h][m][c] */
__global__ __launch_bounds__(256) void k_gemm1b(const float* __restrict__ A,
                                                const float* __restrict__ B,
                                                __hip_bfloat16* __restrict__ h1b) {
  const int M = N_NODES, N = F1, K = C1;
  __shared__ float As[16][64];
  __shared__ float Bs[16][64];
  int tid = threadIdx.x;
  int tx = tid & 15, ty = tid >> 4;
  int m0 = blockIdx.y * 64, n0 = blockIdx.x * 64;
  float acc[4][4] = {};
  for (int k0 = 0; k0 < K; k0 += 16) {
#pragma unroll
    for (int i = 0; i < 4; i++) {
      int li = tid * 4 + i;
      int r = li >> 4, c = li & 15;
      float v = 0.f;
      if (m0 + r < M && k0 + c < K) v = A[(size_t)(m0 + r) * K + k0 + c];
      As[c][r] = v;
    }
#pragma unroll
    for (int i = 0; i < 4; i++) {
      int li = tid * 4 + i;
      int kk = li >> 6, j = li & 63;
      float v = 0.f;
      if (k0 + kk < K && n0 + j < N) v = B[(size_t)(k0 + kk) * N + n0 + j];
      Bs[kk][j] = v;
    }
    __syncthreads();
#pragma unroll
    for (int kk = 0; kk < 16; kk++) {
      float a[4], b[4];
#pragma unroll
      for (int i = 0; i < 4; i++) a[i] = As[kk][ty * 4 + i];
#pragma unroll
      for (int i = 0; i < 4; i++) b[i] = Bs[kk][tx * 4 + i];
#pragma unroll
      for (int i = 0; i < 4; i++)
#pragma unroll
        for (int j = 0; j < 4; j++) acc[i][j] += a[i] * b[j];
    }
    __syncthreads();
  }
  for (int i = 0; i < 4; i++) {
    int m = m0 + ty * 4 + i;
    if (m >= M) continue;
    for (int j = 0; j < 4; j++) {
      int n = n0 + tx * 4 + j;
      if (n < N) {
        int h = n / C1, c = n - h * C1;
        h1b[((size_t)h * N_NODES + m) * C1 + c] = __float2bfloat16(acc[i][j]);
      }
    }
  }
}

/* ---------------- attention logits layer 1 from bf16 h1b, head-major tables -------- */

__global__ void k_alpha1b(const __hip_bfloat16* __restrict__ h1b,
                          const float* __restrict__ a_src, const float* __restrict__ a_dst,
                          float* __restrict__ asb, float* __restrict__ adb) {
  int t = blockIdx.x * blockDim.x + threadIdx.x;
  if (t >= N_NODES * H1) return;
  int h = t / N_NODES;
  const unsigned int* row = (const unsigned int*)(h1b + (size_t)t * C1);
  const float* wsv = a_src + h * C1;
  const float* wdv = a_dst + h * C1;
  float s0 = 0.f, s1 = 0.f;
#pragma unroll
  for (int i = 0; i < C1 / 2; i++) {
    unsigned int u = row[i];
    float lo = bf_lo(u), hi = bf_hi(u);
    s0 += lo * wsv[2 * i] + hi * wsv[2 * i + 1];
    s1 += lo * wdv[2 * i] + hi * wdv[2 * i + 1];
  }
  asb[t] = s0; adb[t] = s1;
}

__global__ void k_alpha2(const float* __restrict__ z2, const float* __restrict__ a_src,
                         const float* __restrict__ a_dst, float* __restrict__ as,
                         float* __restrict__ ad) {
  int n = blockIdx.x * blockDim.x + threadIdx.x;
  if (n >= N_NODES) return;
  const float* row = z2 + (size_t)n * C2;
  float s0 = 0.f, s1 = 0.f;
  for (int c = 0; c < C2; c++) { float v = row[c]; s0 += v * a_src[c]; s1 += v * a_dst[c]; }
  as[n] = s0; ad[n] = s1;
}

/* ---------------- layer-1 GAT: wave per (head,dst), head-phased for L2 locality -------- */

__global__ __launch_bounds__(256) void k_gat1b(const __hip_bfloat16* __restrict__ h1b,
                                               const float* __restrict__ asb,
                                               const float* __restrict__ adb,
                                               const int* __restrict__ offs,
                                               const int* __restrict__ srcs,
                                               const float* __restrict__ b1,
                                               float* __restrict__ ha) {
  int wid = (blockIdx.x * 256 + threadIdx.x) >> 6;
  int lane = threadIdx.x & 63;
  if (wid >= N_NODES * H1) return;
  int h = wid / N_NODES, n = wid - h * N_NODES;
  int beg = offs[n], deg = offs[n + 1] - beg;
  float adv = adb[wid];
  const float* asH = asb + (size_t)h * N_NODES;
  const unsigned int* hrow = (const unsigned int*)(h1b + (size_t)h * N_NODES * C1);

  float acc0 = 0.f, acc1 = 0.f;

  if (deg <= 64) {
    /* fast path: one edge per lane, weights stay in registers */
    float e = -INFINITY; int s = 0;
    if (lane < deg) {
      s = srcs[beg + lane];
      e = asH[s] + adv;
      e = (e > 0.f) ? e : NEG_SLOPE * e;
    }
    float m = e;
#pragma unroll
    for (int o = 32; o; o >>= 1) m = fmaxf(m, __shfl_xor(m, o));
    float p = (lane < deg) ? __expf(e - m) : 0.f;
    float ssum = p;
#pragma unroll
    for (int o = 32; o; o >>= 1) ssum += __shfl_xor(ssum, o);
    p *= 1.f / (ssum + 1e-16f);

    for (int j = 0; j < deg; j += 2) {
      int s0 = __shfl(s, j); float w0 = __shfl(p, j);
      int j1 = (j + 1 < deg) ? j + 1 : j;
      int s1 = __shfl(s, j1); float w1 = (j + 1 < deg) ? __shfl(p, j1) : 0.f;
      if (lane < C1 / 2) {
        unsigned int u0 = hrow[(size_t)s0 * (C1 / 2) + lane];
        unsigned int u1 = hrow[(size_t)s1 * (C1 / 2) + lane];
        acc0 += w0 * bf_lo(u0) + w1 * bf_lo(u1);
        acc1 += w0 * bf_hi(u0) + w1 * bf_hi(u1);
      }
    }
  } else {
    /* general path */
    float m = -INFINITY;
    for (int i = lane; i < deg; i += 64) {
      float e = asH[srcs[beg + i]] + adv;
      e = (e > 0.f) ? e : NEG_SLOPE * e;
      m = fmaxf(m, e);
    }
#pragma unroll
    for (int o = 32; o; o >>= 1) m = fmaxf(m, __shfl_xor(m, o));
    float ssum = 0.f;
    for (int i = lane; i < deg; i += 64) {
      float e = asH[srcs[beg + i]] + adv;
      e = (e > 0.f) ? e : NEG_SLOPE * e;
      ssum += __expf(e - m);
    }
#pragma unroll
    for (int o = 32; o; o >>= 1) ssum += __shfl_xor(ssum, o);
    float inv = 1.f / (ssum + 1e-16f);
    for (int chunk = 0; chunk < deg; chunk += 64) {
      int i = chunk + lane;
      float w = 0.f; int s = 0;
      if (i < deg) {
        s = srcs[beg + i];
        float e = asH[s] + adv;
        e = (e > 0.f) ? e : NEG_SLOPE * e;
        w = __expf(e - m) * inv;
      }
      int cl = min(64, deg - chunk);
      for (int j = 0; j < cl; j++) {
        float wj = __shfl(w, j);
        int sj = __shfl(s, j);
        if (lane < C1 / 2) {
          unsigned int u = hrow[(size_t)sj * (C1 / 2) + lane];
          acc0 += wj * bf_lo(u);
          acc1 += wj * bf_hi(u);
        }
      }
    }
  }

  if (lane < C1 / 2) {
    int c = 2 * lane;
    float v0 = acc0 + b1[h * C1 + c];
    float v1 = acc1 + b1[h * C1 + c + 1];
    v0 = (v0 > 0.f) ? v0 : (__expf(v0) - 1.f);
    v1 = (v1 > 0.f) ? v1 : (__expf(v1) - 1.f);
    float2 o2 = make_float2(v0, v1);
    *(float2*)(ha + (size_t)n * F1 + h * C1 + c) = o2;
  }
}

/* ---------------- layer-2 GAT: wave per dst, 1 head, 100 ch, + bias + ReLU ---------------- */

__global__ __launch_bounds__(256) void k_gat2(const float* __restrict__ z2,
                                              const float* __restrict__ as,
                                              const float* __restrict__ ad,
                                              const int* __restrict__ offs,
                                              const int* __restrict__ srcs,
                                              const float* __restrict__ b2,
                                              float* __restrict__ h2) {
  int wid = (blockIdx.x * 256 + threadIdx.x) >> 6;
  int lane = threadIdx.x & 63;
  if (wid >= N_NODES) return;
  int n = wid;
  int beg = offs[n], deg = offs[n + 1] - beg;
  float adv = ad[n];

  float acc0 = 0.f, acc1 = 0.f;

  if (deg <= 64) {
    float e = -INFINITY; int s = 0;
    if (lane < deg) {
      s = srcs[beg + lane];
      e = as[s] + adv;
      e = (e > 0.f) ? e : NEG_SLOPE * e;
    }
    float m = e;
#pragma unroll
    for (int o = 32; o; o >>= 1) m = fmaxf(m, __shfl_xor(m, o));
    float p = (lane < deg) ? __expf(e - m) : 0.f;
    float ssum = p;
#pragma unroll
    for (int o = 32; o; o >>= 1) ssum += __shfl_xor(ssum, o);
    p *= 1.f / (ssum + 1e-16f);
    for (int j = 0; j < deg; j++) {
      float wj = __shfl(p, j);
      int sj = __shfl(s, j);
      const float* row = z2 + (size_t)sj * C2;
      acc0 += wj * row[lane];
      if (lane < C2 - 64) acc1 += wj * row[64 + lane];
    }
  } else {
    float m = -INFINITY;
    for (int i = lane; i < deg; i += 64) {
      float e = as[srcs[beg + i]] + adv;
      e = (e > 0.f) ? e : NEG_SLOPE * e;
      m = fmaxf(m, e);
    }
#pragma unroll
    for (int o = 32; o; o >>= 1) m = fmaxf(m, __shfl_xor(m, o));
    float ssum = 0.f;
    for (int i = lane; i < deg; i += 64) {
      float e = as[srcs[beg + i]] + adv;
      e = (e > 0.f) ? e : NEG_SLOPE * e;
      ssum += __expf(e - m);
    }
#pragma unroll
    for (int o = 32; o; o >>= 1) ssum += __shfl_xor(ssum, o);
    float inv = 1.f / (ssum + 1e-16f);
    for (int chunk = 0; chunk < deg; chunk += 64) {
      int i = chunk + lane;
      float w = 0.f; int s = 0;
      if (i < deg) {
        s = srcs[beg + i];
        float e = as[s] + adv;
        e = (e > 0.f) ? e : NEG_SLOPE * e;
        w = __expf(e - m) * inv;
      }
      int cl = min(64, deg - chunk);
      for (int j = 0; j < cl; j++) {
        float wj = __shfl(w, j);
        int sj = __shfl(s, j);
        const float* row = z2 + (size_t)sj * C2;
        acc0 += wj * row[lane];
        if (lane < C2 - 64) acc1 += wj * row[64 + lane];
      }
    }
  }

  float v0 = acc0 + b2[lane];
  h2[(size_t)n * C2 + lane] = fmaxf(v0, 0.f);
  if (lane < C2 - 64) {
    float v1 = acc1 + b2[64 + lane];
    h2[(size_t)n * C2 + 64 + lane] = fmaxf(v1, 0.f);
  }
}

/* ---------------- global max pool (h2 >= 0, so uint atomicMax with 0-init is exact) -------- */

__global__ void k_pool(const float* __restrict__ h2, const int* __restrict__ batch,
                       unsigned int* __restrict__ pool) {
  int t = blockIdx.x * blockDim.x + threadIdx.x;
  if (t >= N_NODES * C2) return;
  int n = t / C2, c = t % C2;
  int g = batch[n];
  atomicMax(&pool[g * C2 + c], __float_as_uint(h2[t]));
}

/* ---------------- head: out = relu(pool @ Wg + bg) ---------------- */

__global__ __launch_bounds__(128) void k_head(const float* __restrict__ pool,
                                              const float* __restrict__ Wg,
                                              const float* __restrict__ bg,
                                              float* __restrict__ out) {
  __shared__ float row[C2];
  int g = blockIdx.x;
  if (threadIdx.x < C2) row[threadIdx.x] = pool[g * C2 + threadIdx.x];
  __syncthreads();
  int c = threadIdx.x;
  if (c < C2) {
    float acc = bg[c];
    for (int k = 0; k < C2; k++) acc += row[k] * Wg[k * C2 + c];
    out[g * C2 + c] = fmaxf(acc, 0.f);
  }
}

/* ---------------- launch ---------------- */

extern "C" void kernel_launch(void* const* d_in, const int* in_sizes, int n_in,
                              void* d_out, int out_size, void* d_ws, size_t ws_size,
                              hipStream_t stream) {
  const float* x      = (const float*)d_in[0];
  const int*   ei     = (const int*)d_in[1];
  const int*   batch  = (const int*)d_in[2];
  const float* W1     = (const float*)d_in[4];
  const float* a_src1 = (const float*)d_in[5];
  const float* a_dst1 = (const float*)d_in[6];
  const float* b1     = (const float*)d_in[7];
  const float* W2     = (const float*)d_in[8];
  const float* a_src2 = (const float*)d_in[9];
  const float* a_dst2 = (const float*)d_in[10];
  const float* b2     = (const float*)d_in[11];
  const float* Wg     = (const float*)d_in[12];
  const float* bg     = (const float*)d_in[13];
  float* out = (float*)d_out;

  char* w = (char*)d_ws;
  size_t off = 0;
  auto alloc = [&](size_t bytes) -> void* {
    void* p = w + off;
    off += (bytes + 255) & ~(size_t)255;
    return p;
  };

  __hip_bfloat16* h1b = (__hip_bfloat16*)alloc((size_t)H1 * N_NODES * C1 * 2); /* 31.2 MB */
  float* ha  = (float*)alloc((size_t)N_NODES * F1 * 4);                        /* 62.4 MB */
  float* as1 = (float*)alloc((size_t)N_NODES * H1 * 4);
  float* ad1 = (float*)alloc((size_t)N_NODES * H1 * 4);
  int* cnt    = (int*)alloc((size_t)N_NODES * 4);
  int* cursor = (int*)alloc((size_t)N_NODES * 4);
  int* offs   = (int*)alloc((size_t)(N_NODES + 1) * 4);
  int* srcs   = (int*)alloc((size_t)E_TOT * 4);

  /* layer-2 buffers alias dead h1b region (h1b unused after k_gat1b) */
  float* z2  = (float*)h1b;                     /* 20000*100 = 8 MB */
  float* h2  = z2 + (size_t)N_NODES * C2;       /* 8 MB */
  float* as2 = h2 + (size_t)N_NODES * C2;
  float* ad2 = as2 + N_NODES;
  unsigned int* pool = (unsigned int*)(ad2 + N_NODES);

  hipMemsetAsync(cnt, 0, (size_t)N_NODES * 4, stream);
  hipMemsetAsync(cursor, 0, (size_t)N_NODES * 4, stream);

  k_count<<<(E_TOT + 255) / 256, 256, 0, stream>>>(ei, cnt);
  k_scan<<<1, 1024, 0, stream>>>(cnt, offs, N_NODES);
  k_scatter<<<(E_TOT + 255) / 256, 256, 0, stream>>>(ei, offs, cursor, srcs);

  /* GEMM1: h1b[h][n][c] = bf16(x @ W1)  (20000x780x78) */
  k_gemm1b<<<dim3((F1 + 63) / 64, (N_NODES + 63) / 64), 256, 0, stream>>>(x, W1, h1b);
  k_alpha1b<<<(N_NODES * H1 + 255) / 256, 256, 0, stream>>>(h1b, a_src1, a_dst1, as1, ad1);
  k_gat1b<<<(N_NODES * H1) / 4, 256, 0, stream>>>(h1b, as1, ad1, offs, srcs, b1, ha);

  /* GEMM2: z2 = ha @ W2   (20000x100x780) -- z2 aliases h1b (dead) */
  k_gemm<<<dim3((C2 + 63) / 64, (N_NODES + 63) / 64), 256, 0, stream>>>(ha, W2, z2,
                                                                        N_NODES, C2, F1);
  k_alpha2<<<(N_NODES + 255) / 256, 256, 0, stream>>>(z2, a_src2, a_dst2, as2, ad2);
  k_gat2<<<N_NODES / 4, 256, 0, stream>>>(z2, as2, ad2, offs, srcs, b2, h2);

  hipMemsetAsync(pool, 0, (size_t)N_GRAPHS * C2 * 4, stream);
  k_pool<<<(N_NODES * C2 + 255) / 256, 256, 0, stream>>>(h2, batch, pool);
  k_head<<<N_GRAPHS, 128, 0, stream>>>((const float*)pool, Wg, bg, out);
}